// Round 1
// baseline (640.150 us; speedup 1.0000x reference)
//
#include <hip/hip_runtime.h>
#include <hip/hip_bf16.h>

// GQA fused block for MI355X (gfx950).
// Pipeline: transpose+cvt weights -> bf16 MFMA GEMMs (QKV proj) -> RMSNorm(q,k)
//           -> causal GQA flash attention (bf16 MFMA, fp32 softmax) -> output GEMM.
// B=2, S=2048, E=2048, H=16, G=2 (GQA group 8), D=128.

typedef short  bf16x8 __attribute__((ext_vector_type(8)));   // 8 bf16 in 4 VGPRs (MFMA frag)
typedef float  f32x4  __attribute__((ext_vector_type(4)));
typedef unsigned short u16x8 __attribute__((ext_vector_type(8)));

static __device__ __forceinline__ unsigned short f2bf(float f) {
    __hip_bfloat16 h = __float2bfloat16(f);   // RNE
    return *reinterpret_cast<unsigned short*>(&h);
}

// ---------------- transpose + convert: W [K][N] f32 -> Wt [N][K] bf16 ----------------
__global__ __launch_bounds__(256)
void transpose_cvt(const float* __restrict__ W, unsigned short* __restrict__ Wt,
                   int K, int N) {
    __shared__ float t[32][33];
    int n0 = blockIdx.x * 32, k0 = blockIdx.y * 32;
    int tx = threadIdx.x & 31, ty = threadIdx.x >> 5;     // 32 x 8
#pragma unroll
    for (int i = 0; i < 32; i += 8)
        t[ty + i][tx] = W[(size_t)(k0 + ty + i) * N + n0 + tx];
    __syncthreads();
#pragma unroll
    for (int i = 0; i < 32; i += 8)
        Wt[(size_t)(n0 + ty + i) * K + k0 + tx] = f2bf(t[tx][ty + i]);
}

// ---------------- GEMM: C[M][N] = A[M][K] @ W + bias;  W given as Wt[N][K] bf16 -------
// A_F32: A is f32 (converted during staging), else bf16.
// OUT_BF16: write bf16, else f32.
template<bool A_F32, bool OUT_BF16>
__global__ __launch_bounds__(256)
void gemm_bt(const void* __restrict__ Ain, const unsigned short* __restrict__ Bt,
             const float* __restrict__ bias, void* __restrict__ Cout,
             int M, int N, int K) {
    const int BK = 32;
    __shared__ unsigned short Al[128][40];   // pad->80B rows (16B aligned, spread banks)
    __shared__ unsigned short Bl[128][40];
    int m0 = blockIdx.y * 128, n0 = blockIdx.x * 128;
    int tid = threadIdx.x;
    int lane = tid & 63, wid = tid >> 6;
    int wr = wid >> 1, wc = wid & 1;          // 2x2 wave grid, 64x64 out per wave
    int lg = lane >> 4, lr = lane & 15;

    f32x4 acc[4][4];
#pragma unroll
    for (int i = 0; i < 4; i++)
#pragma unroll
        for (int j = 0; j < 4; j++) acc[i][j] = f32x4{0.f, 0.f, 0.f, 0.f};

    int sr = tid >> 2;        // 0..63  staging row
    int sc = tid & 3;         // k chunk: elements 8*sc..8*sc+7

    for (int k0 = 0; k0 < K; k0 += BK) {
        u16x8 va0, va1;
        if (A_F32) {
            const float* a0 = (const float*)Ain + (size_t)(m0 + sr) * K + k0 + 8 * sc;
            const float* a1 = (const float*)Ain + (size_t)(m0 + sr + 64) * K + k0 + 8 * sc;
            float4 x0 = *(const float4*)a0, x1 = *(const float4*)(a0 + 4);
            float4 y0 = *(const float4*)a1, y1 = *(const float4*)(a1 + 4);
            va0 = u16x8{f2bf(x0.x), f2bf(x0.y), f2bf(x0.z), f2bf(x0.w),
                        f2bf(x1.x), f2bf(x1.y), f2bf(x1.z), f2bf(x1.w)};
            va1 = u16x8{f2bf(y0.x), f2bf(y0.y), f2bf(y0.z), f2bf(y0.w),
                        f2bf(y1.x), f2bf(y1.y), f2bf(y1.z), f2bf(y1.w)};
        } else {
            va0 = *(const u16x8*)((const unsigned short*)Ain + (size_t)(m0 + sr) * K + k0 + 8 * sc);
            va1 = *(const u16x8*)((const unsigned short*)Ain + (size_t)(m0 + sr + 64) * K + k0 + 8 * sc);
        }
        u16x8 vb0 = *(const u16x8*)(Bt + (size_t)(n0 + sr) * K + k0 + 8 * sc);
        u16x8 vb1 = *(const u16x8*)(Bt + (size_t)(n0 + sr + 64) * K + k0 + 8 * sc);
        *(u16x8*)&Al[sr][8 * sc] = va0;
        *(u16x8*)&Al[sr + 64][8 * sc] = va1;
        *(u16x8*)&Bl[sr][8 * sc] = vb0;
        *(u16x8*)&Bl[sr + 64][8 * sc] = vb1;
        __syncthreads();

        bf16x8 af[4], bfr[4];
#pragma unroll
        for (int mi = 0; mi < 4; mi++)
            af[mi] = *(const bf16x8*)&Al[wr * 64 + mi * 16 + lr][8 * lg];
#pragma unroll
        for (int ni = 0; ni < 4; ni++)
            bfr[ni] = *(const bf16x8*)&Bl[wc * 64 + ni * 16 + lr][8 * lg];
#pragma unroll
        for (int mi = 0; mi < 4; mi++)
#pragma unroll
            for (int ni = 0; ni < 4; ni++)
                acc[mi][ni] = __builtin_amdgcn_mfma_f32_16x16x32_bf16(af[mi], bfr[ni], acc[mi][ni], 0, 0, 0);
        __syncthreads();
    }

#pragma unroll
    for (int mi = 0; mi < 4; mi++) {
#pragma unroll
        for (int ni = 0; ni < 4; ni++) {
            int col = n0 + wc * 64 + ni * 16 + lr;
            float bv = bias[col];
#pragma unroll
            for (int r = 0; r < 4; r++) {
                int row = m0 + wr * 64 + mi * 16 + 4 * lg + r;
                float v = acc[mi][ni][r] + bv;
                if (OUT_BF16)
                    ((unsigned short*)Cout)[(size_t)row * N + col] = f2bf(v);
                else
                    ((float*)Cout)[(size_t)row * N + col] = v;
            }
        }
    }
}

// ---------------- RMSNorm per 128-chunk + cvt to bf16 --------------------------------
__global__ __launch_bounds__(256)
void rmsnorm_cvt(const float* __restrict__ X, const float* __restrict__ gamma,
                 unsigned short* __restrict__ Y, int nchunks) {
    int wave = blockIdx.x * 4 + (threadIdx.x >> 6);
    int lane = threadIdx.x & 63;
    if (wave >= nchunks) return;
    float2 v = *(const float2*)(X + (size_t)wave * 128 + lane * 2);
    float ss = v.x * v.x + v.y * v.y;
#pragma unroll
    for (int m = 1; m < 64; m <<= 1) ss += __shfl_xor(ss, m);
    float inv = rsqrtf(ss * (1.0f / 128.0f) + 1e-8f);
    float2 gv = *(const float2*)(gamma + lane * 2);
    unsigned short o0 = f2bf(v.x * inv * gv.x);
    unsigned short o1 = f2bf(v.y * inv * gv.y);
    ((unsigned int*)Y)[(size_t)wave * 64 + lane] = (unsigned)o0 | ((unsigned)o1 << 16);
}

// ---------------- causal GQA flash attention ----------------------------------------
// grid (S/128, H, B), 256 threads. Wave w owns q rows q0+w*32..+31 (2 MFMA row-blocks).
__global__ __launch_bounds__(256)
void attn_kernel(const unsigned short* __restrict__ Qb,   // [B*S][2048] bf16 (normed)
                 const unsigned short* __restrict__ Kb,   // [B*S][256]  bf16 (normed)
                 const unsigned short* __restrict__ Vb,   // [B*S][256]  bf16
                 unsigned short* __restrict__ Ctx) {      // [B*S][2048] bf16
    const int S = 2048;
    int qblk = blockIdx.x;                 // 0..15 (128 q rows each)
    int h = blockIdx.y;
    int b = blockIdx.z;
    int g = h >> 3;
    int tid = threadIdx.x, lane = tid & 63, w = tid >> 6;
    int lg = lane >> 4, lr = lane & 15;
    int q0 = qblk * 128;
    size_t tok0 = (size_t)b * S;

    __shared__ unsigned short Kl[64][136];     // [kv][d], 272B rows
    __shared__ unsigned short Vt[128][72];     // [d][kv], 144B rows
    __shared__ unsigned short Pl[4][32][72];   // per-wave P, [row][kv]

    // Q fragments in registers: rows q0 + w*32 + mi*16 + lr
    bf16x8 qf[2][4];
#pragma unroll
    for (int mi = 0; mi < 2; mi++) {
        const unsigned short* qrow = Qb + (tok0 + q0 + w * 32 + mi * 16 + lr) * 2048 + h * 128;
#pragma unroll
        for (int ks = 0; ks < 4; ks++)
            qf[mi][ks] = *(const bf16x8*)(qrow + ks * 32 + 8 * lg);
    }

    f32x4 o[2][8];
#pragma unroll
    for (int mi = 0; mi < 2; mi++)
#pragma unroll
        for (int t = 0; t < 8; t++) o[mi][t] = f32x4{0.f, 0.f, 0.f, 0.f};
    float mrow[2][4], lrow[2][4];
#pragma unroll
    for (int mi = 0; mi < 2; mi++)
#pragma unroll
        for (int r = 0; r < 4; r++) { mrow[mi][r] = -1e30f; lrow[mi][r] = 0.f; }

    const float cexp = 0.08838834764831845f * 1.4426950408889634f; // 1/sqrt(128)*log2(e)
    int nkv = 2 * qblk + 2;

    for (int kvt = 0; kvt < nkv; kvt++) {
        int kv0 = kvt * 64;
        // ---- stage K [64][128] coalesced
        {
            int sr = tid >> 2, sc = tid & 3;
            const unsigned short* krow = Kb + (tok0 + kv0 + sr) * 256 + g * 128;
#pragma unroll
            for (int i = 0; i < 4; i++) {
                u16x8 v = *(const u16x8*)(krow + sc * 32 + i * 8);
                *(u16x8*)&Kl[sr][sc * 32 + i * 8] = v;
            }
            // ---- stage V transposed: Vt[d][kv]
            int vr = tid & 63, dc = tid >> 6;
            const unsigned short* vrow = Vb + (tok0 + kv0 + vr) * 256 + g * 128;
#pragma unroll
            for (int i = 0; i < 4; i++) {
                u16x8 v = *(const u16x8*)(vrow + dc * 32 + i * 8);
#pragma unroll
                for (int j = 0; j < 8; j++) Vt[dc * 32 + i * 8 + j][vr] = v[j];
            }
        }
        __syncthreads();

        // ---- S = Q K^T  (per wave: 32 q-rows x 64 kv)
        f32x4 sacc[2][4];
#pragma unroll
        for (int mi = 0; mi < 2; mi++)
#pragma unroll
            for (int c = 0; c < 4; c++) sacc[mi][c] = f32x4{0.f, 0.f, 0.f, 0.f};
#pragma unroll
        for (int c = 0; c < 4; c++) {
#pragma unroll
            for (int ks = 0; ks < 4; ks++) {
                bf16x8 kfr = *(const bf16x8*)&Kl[c * 16 + lr][ks * 32 + 8 * lg];
                sacc[0][c] = __builtin_amdgcn_mfma_f32_16x16x32_bf16(qf[0][ks], kfr, sacc[0][c], 0, 0, 0);
                sacc[1][c] = __builtin_amdgcn_mfma_f32_16x16x32_bf16(qf[1][ks], kfr, sacc[1][c], 0, 0, 0);
            }
        }

        // ---- online softmax (rows live in 16-lane groups; butterfly over lr)
        bool diag = (kvt >= 2 * qblk);
        float p[2][4][4];      // [mi][c][r]
        float tmax[2][4];
#pragma unroll
        for (int mi = 0; mi < 2; mi++)
#pragma unroll
            for (int r = 0; r < 4; r++) tmax[mi][r] = -1e30f;
#pragma unroll
        for (int mi = 0; mi < 2; mi++)
#pragma unroll
            for (int c = 0; c < 4; c++)
#pragma unroll
                for (int r = 0; r < 4; r++) {
                    float s = sacc[mi][c][r] * cexp;
                    if (diag) {
                        int qi = q0 + w * 32 + mi * 16 + 4 * lg + r;
                        int ki = kv0 + c * 16 + lr;
                        if (ki > qi) s = -1e30f;
                    }
                    p[mi][c][r] = s;
                    tmax[mi][r] = fmaxf(tmax[mi][r], s);
                }
#pragma unroll
        for (int m = 1; m < 16; m <<= 1)
#pragma unroll
            for (int mi = 0; mi < 2; mi++)
#pragma unroll
                for (int r = 0; r < 4; r++)
                    tmax[mi][r] = fmaxf(tmax[mi][r], __shfl_xor(tmax[mi][r], m));

        float alpha[2][4], tsum[2][4];
#pragma unroll
        for (int mi = 0; mi < 2; mi++)
#pragma unroll
            for (int r = 0; r < 4; r++) {
                float mn = fmaxf(mrow[mi][r], tmax[mi][r]);
                alpha[mi][r] = __builtin_exp2f(mrow[mi][r] - mn);
                mrow[mi][r] = mn;
                tsum[mi][r] = 0.f;
            }
#pragma unroll
        for (int mi = 0; mi < 2; mi++)
#pragma unroll
            for (int c = 0; c < 4; c++)
#pragma unroll
                for (int r = 0; r < 4; r++) {
                    float e = __builtin_exp2f(p[mi][c][r] - mrow[mi][r]);
                    p[mi][c][r] = e;
                    tsum[mi][r] += e;
                }
#pragma unroll
        for (int m = 1; m < 16; m <<= 1)
#pragma unroll
            for (int mi = 0; mi < 2; mi++)
#pragma unroll
                for (int r = 0; r < 4; r++)
                    tsum[mi][r] += __shfl_xor(tsum[mi][r], m);
#pragma unroll
        for (int mi = 0; mi < 2; mi++)
#pragma unroll
            for (int r = 0; r < 4; r++)
                lrow[mi][r] = lrow[mi][r] * alpha[mi][r] + tsum[mi][r];
#pragma unroll
        for (int mi = 0; mi < 2; mi++)
#pragma unroll
            for (int t = 0; t < 8; t++)
#pragma unroll
                for (int r = 0; r < 4; r++) o[mi][t][r] *= alpha[mi][r];

        // ---- P -> LDS (bf16, per-wave private: no barrier needed)
#pragma unroll
        for (int mi = 0; mi < 2; mi++)
#pragma unroll
            for (int c = 0; c < 4; c++)
#pragma unroll
                for (int r = 0; r < 4; r++)
                    Pl[w][mi * 16 + 4 * lg + r][c * 16 + lr] = f2bf(p[mi][c][r]);

        // ---- O += P V
#pragma unroll
        for (int ks = 0; ks < 2; ks++) {
            bf16x8 pf0 = *(const bf16x8*)&Pl[w][lr][ks * 32 + 8 * lg];
            bf16x8 pf1 = *(const bf16x8*)&Pl[w][16 + lr][ks * 32 + 8 * lg];
#pragma unroll
            for (int t = 0; t < 8; t++) {
                bf16x8 vf = *(const bf16x8*)&Vt[t * 16 + lr][ks * 32 + 8 * lg];
                o[0][t] = __builtin_amdgcn_mfma_f32_16x16x32_bf16(pf0, vf, o[0][t], 0, 0, 0);
                o[1][t] = __builtin_amdgcn_mfma_f32_16x16x32_bf16(pf1, vf, o[1][t], 0, 0, 0);
            }
        }
        __syncthreads();
    }

    // ---- epilogue: O / l -> bf16
#pragma unroll
    for (int mi = 0; mi < 2; mi++) {
        unsigned short* crow = Ctx + (tok0 + q0 + w * 32 + mi * 16) * 2048 + h * 128;
#pragma unroll
        for (int r = 0; r < 4; r++) {
            float inv = 1.0f / lrow[mi][r];
            int row = 4 * lg + r;
#pragma unroll
            for (int t = 0; t < 8; t++)
                crow[(size_t)row * 2048 + t * 16 + lr] = f2bf(o[mi][t][r] * inv);
        }
    }
}

// ---------------- launch --------------------------------------------------------------
extern "C" void kernel_launch(void* const* d_in, const int* in_sizes, int n_in,
                              void* d_out, int out_size, void* d_ws, size_t ws_size,
                              hipStream_t stream) {
    const float* x  = (const float*)d_in[0];
    const float* Wq = (const float*)d_in[1];
    const float* bq = (const float*)d_in[2];
    const float* Wk = (const float*)d_in[3];
    const float* bk = (const float*)d_in[4];
    const float* Wv = (const float*)d_in[5];
    const float* bv = (const float*)d_in[6];
    const float* gq = (const float*)d_in[7];
    const float* gk = (const float*)d_in[8];
    const float* Wo = (const float*)d_in[9];
    const float* bo = (const float*)d_in[10];
    float* out = (float*)d_out;

    char* ws = (char*)d_ws;
    size_t off = 0;
    auto alloc = [&](size_t bytes) {
        void* p = ws + off;
        off += (bytes + 255) & ~(size_t)255;
        return p;
    };
    unsigned short* wqt = (unsigned short*)alloc((size_t)2048 * 2048 * 2);
    unsigned short* wkt = (unsigned short*)alloc((size_t)256 * 2048 * 2);
    unsigned short* wvt = (unsigned short*)alloc((size_t)256 * 2048 * 2);
    unsigned short* wot = (unsigned short*)alloc((size_t)2048 * 2048 * 2);
    float*          qf  = (float*)alloc((size_t)4096 * 2048 * 4);
    float*          kf  = (float*)alloc((size_t)4096 * 256 * 4);
    unsigned short* qb_ = (unsigned short*)alloc((size_t)4096 * 2048 * 2);
    unsigned short* kb_ = (unsigned short*)alloc((size_t)4096 * 256 * 2);
    unsigned short* vb_ = (unsigned short*)alloc((size_t)4096 * 256 * 2);
    unsigned short* ctx = (unsigned short*)alloc((size_t)4096 * 2048 * 2);

    // weights -> K-major bf16
    transpose_cvt<<<dim3(64, 64), 256, 0, stream>>>(Wq, wqt, 2048, 2048);
    transpose_cvt<<<dim3(8, 64), 256, 0, stream>>>(Wk, wkt, 2048, 256);
    transpose_cvt<<<dim3(8, 64), 256, 0, stream>>>(Wv, wvt, 2048, 256);
    transpose_cvt<<<dim3(64, 64), 256, 0, stream>>>(Wo, wot, 2048, 2048);

    // projections
    gemm_bt<true, false><<<dim3(16, 32), 256, 0, stream>>>(x, wqt, bq, qf, 4096, 2048, 2048);
    gemm_bt<true, false><<<dim3(2, 32), 256, 0, stream>>>(x, wkt, bk, kf, 4096, 256, 2048);
    gemm_bt<true, true><<<dim3(2, 32), 256, 0, stream>>>(x, wvt, bv, vb_, 4096, 256, 2048);

    // per-head RMSNorm + cvt
    rmsnorm_cvt<<<16384, 256, 0, stream>>>(qf, gq, qb_, 65536);
    rmsnorm_cvt<<<2048, 256, 0, stream>>>(kf, gk, kb_, 8192);

    // attention
    attn_kernel<<<dim3(16, 16, 2), 256, 0, stream>>>(qb_, kb_, vb_, ctx);

    // output projection -> f32 out
    gemm_bt<false, false><<<dim3(16, 32), 256, 0, stream>>>(ctx, wot, bo, out, 4096, 2048, 2048);
}

// Round 2
// 373.794 us; speedup vs baseline: 1.7126x; 1.7126x over previous
//
#include <hip/hip_runtime.h>
#include <hip/hip_bf16.h>

// GQA fused block, MI355X. B=2,S=2048,E=2048,H=16,G=2,D=128.
// x->bf16 ; W^T bf16 ; fused QKV GEMM (global_load_lds) -> C f32 ;
// rmsnorm q,k -> bf16 ; V^T transpose ; paired-tile flash attention
// (uniform work, swizzled LDS) ; out GEMM.

typedef short  bf16x8 __attribute__((ext_vector_type(8)));
typedef float  f32x4  __attribute__((ext_vector_type(4)));
typedef unsigned short u16x8 __attribute__((ext_vector_type(8)));

static __device__ __forceinline__ unsigned short f2bf(float f) {
    __hip_bfloat16 h = __float2bfloat16(f);   // RNE
    return *reinterpret_cast<unsigned short*>(&h);
}

static __device__ __forceinline__ void load_lds16(const void* g, void* l) {
    __builtin_amdgcn_global_load_lds(
        (const __attribute__((address_space(1))) void*)g,
        (__attribute__((address_space(3))) void*)l, 16, 0, 0);
}

// ---------------- x f32 -> bf16 ------------------------------------------------------
__global__ __launch_bounds__(256)
void cvt_bf16_k(const float* __restrict__ X, unsigned short* __restrict__ Y, int n8) {
    int i = blockIdx.x * 256 + threadIdx.x;
    if (i >= n8) return;
    float4 a = *(const float4*)(X + (size_t)i * 8);
    float4 b = *(const float4*)(X + (size_t)i * 8 + 4);
    u16x8 o{f2bf(a.x), f2bf(a.y), f2bf(a.z), f2bf(a.w),
            f2bf(b.x), f2bf(b.y), f2bf(b.z), f2bf(b.w)};
    *(u16x8*)(Y + (size_t)i * 8) = o;
}

// ---------------- strided transpose + cvt: W[k][n] (row stride in_stride) -> Wt[n][k] -
__global__ __launch_bounds__(256)
void transpose_cvt2(const float* __restrict__ W, unsigned short* __restrict__ Wt,
                    int in_stride, int K) {
    __shared__ float t[32][33];
    int n0 = blockIdx.x * 32, k0 = blockIdx.y * 32;
    int tx = threadIdx.x & 31, ty = threadIdx.x >> 5;     // 32 x 8
#pragma unroll
    for (int i = 0; i < 32; i += 8)
        t[ty + i][tx] = W[(size_t)(k0 + ty + i) * in_stride + n0 + tx];
    __syncthreads();
#pragma unroll
    for (int i = 0; i < 32; i += 8)
        Wt[(size_t)(n0 + ty + i) * K + k0 + tx] = f2bf(t[tx][ty + i]);
}

// ---------------- GEMM (m97 structure): C[M][N] f32 = A[M][K]bf16 @ Bt[N][K]bf16 + bias
__global__ __launch_bounds__(256)
void gemm_lds(const unsigned short* __restrict__ A, const unsigned short* __restrict__ Bt,
              const float* __restrict__ bias, float* __restrict__ Cout,
              int M, int N, int K) {
    __shared__ unsigned short Al[128 * 32];   // linear [row][32], 8KB
    __shared__ unsigned short Bl[128 * 32];
    int m0 = blockIdx.y * 128, n0 = blockIdx.x * 128;
    int tid = threadIdx.x, lane = tid & 63, w = tid >> 6;
    int wr = w >> 1, wc = w & 1, lg = lane >> 4, lr = lane & 15;

    f32x4 acc[4][4];
#pragma unroll
    for (int i = 0; i < 4; i++)
#pragma unroll
        for (int j = 0; j < 4; j++) acc[i][j] = f32x4{0.f, 0.f, 0.f, 0.f};

    int srow = w * 16 + (lane >> 2);          // 0..63 within 64-row group
    int scol = (lane & 3) * 8;                // element offset in K
    const unsigned short* ga = A  + (size_t)(m0 + srow) * K + scol;
    const unsigned short* gb = Bt + (size_t)(n0 + srow) * K + scol;
    unsigned short* la = Al + w * 512;        // wave-uniform LDS base (+lane*16B by HW)
    unsigned short* lb = Bl + w * 512;

    for (int k0 = 0; k0 < K; k0 += 32) {
        load_lds16(ga + k0,                    la);
        load_lds16(ga + (size_t)64 * K + k0,   la + 2048);
        load_lds16(gb + k0,                    lb);
        load_lds16(gb + (size_t)64 * K + k0,   lb + 2048);
        __syncthreads();
        bf16x8 af[4], bfv[4];
#pragma unroll
        for (int mi = 0; mi < 4; mi++)
            af[mi] = *(const bf16x8*)&Al[(wr * 64 + mi * 16 + lr) * 32 + 8 * lg];
#pragma unroll
        for (int ni = 0; ni < 4; ni++)
            bfv[ni] = *(const bf16x8*)&Bl[(wc * 64 + ni * 16 + lr) * 32 + 8 * lg];
#pragma unroll
        for (int mi = 0; mi < 4; mi++)
#pragma unroll
            for (int ni = 0; ni < 4; ni++)
                acc[mi][ni] = __builtin_amdgcn_mfma_f32_16x16x32_bf16(af[mi], bfv[ni], acc[mi][ni], 0, 0, 0);
        __syncthreads();
    }

#pragma unroll
    for (int mi = 0; mi < 4; mi++)
#pragma unroll
        for (int ni = 0; ni < 4; ni++) {
            int col = n0 + wc * 64 + ni * 16 + lr;
            float bv = bias[col];
#pragma unroll
            for (int r = 0; r < 4; r++) {
                int row = m0 + wr * 64 + mi * 16 + 4 * lg + r;
                Cout[(size_t)row * N + col] = acc[mi][ni][r] + bv;
            }
        }
}

// ---------------- RMSNorm 128-chunks from strided f32 -> bf16 ------------------------
__global__ __launch_bounds__(256)
void rmsnorm_cvt2(const float* __restrict__ C, const float* __restrict__ gamma,
                  unsigned short* __restrict__ Y, int in_stride, int in_off,
                  int cl, int total) {
    int wave = blockIdx.x * 4 + (threadIdx.x >> 6);
    int lane = threadIdx.x & 63;
    if (wave >= total) return;
    int token = wave >> cl, c = wave & ((1 << cl) - 1);
    const float* in = C + (size_t)token * in_stride + in_off + c * 128;
    float2 v = *(const float2*)(in + lane * 2);
    float ss = v.x * v.x + v.y * v.y;
#pragma unroll
    for (int m = 1; m < 64; m <<= 1) ss += __shfl_xor(ss, m);
    float inv = rsqrtf(ss * (1.0f / 128.0f) + 1e-8f);
    float2 gv = *(const float2*)(gamma + lane * 2);
    unsigned short o0 = f2bf(v.x * inv * gv.x);
    unsigned short o1 = f2bf(v.y * inv * gv.y);
    ((unsigned int*)Y)[((size_t)token * (1 << cl) + c) * 64 + lane] =
        (unsigned)o0 | ((unsigned)o1 << 16);
}

// ---------------- causal GQA flash attention (paired q-tiles, uniform work) ----------
// grid (16 pairs, 16 h, 2 b), 256 thr. Block handles q-tiles {pair, 31-pair} (64 rows
// each); wave w owns 16 rows. K/V staged via global_load_lds, XOR-swizzled LDS.
__global__ __launch_bounds__(256, 3)
void attn_kernel(const unsigned short* __restrict__ Qb,   // [4096][2048] bf16 normed
                 const unsigned short* __restrict__ Kb,   // [4096][256]  bf16 normed
                 const unsigned short* __restrict__ Vt,   // [512][4096]  bf16 V^T
                 unsigned short* __restrict__ Ctx) {      // [4096][2048] bf16
    const int S = 2048;
    int pair = blockIdx.x, h = blockIdx.y, b = blockIdx.z, g = h >> 3;
    int tid = threadIdx.x, lane = tid & 63, w = tid >> 6;
    int lg = lane >> 4, lr = lane & 15;
    size_t tok0 = (size_t)b * S;

    __shared__ unsigned short Kl[64 * 128];    // [kv][128], swizzled, 16KB
    __shared__ unsigned short Vl[128 * 64];    // [d][64kv], swizzled, 16KB
    __shared__ unsigned short Pl[4][16][72];   // per-wave P

    const float cexp = 0.08838834764831845f * 1.4426950408889634f;

    // staging maps (constant across tiles except kv0)
    int krow_l = w * 4 + (lane >> 4);                 // 0..15
    int kc16   = (lane & 15) ^ (krow_l & 7);
    int vrow_l = w * 8 + (lane >> 3);                 // 0..31
    int vc16   = (lane & 7) ^ (vrow_l & 7);

    for (int hf = 0; hf < 2; hf++) {
        int qt = hf ? (31 - pair) : pair;
        int qrow0 = qt * 64 + w * 16;

        bf16x8 qf[4];
#pragma unroll
        for (int ks = 0; ks < 4; ks++)
            qf[ks] = *(const bf16x8*)(Qb + (tok0 + qrow0 + lr) * 2048 + h * 128 + ks * 32 + 8 * lg);

        f32x4 o[8];
#pragma unroll
        for (int t = 0; t < 8; t++) o[t] = f32x4{0.f, 0.f, 0.f, 0.f};
        float mrow[4], lrow[4];
#pragma unroll
        for (int r = 0; r < 4; r++) { mrow[r] = -1e30f; lrow[r] = 0.f; }

        int nkv = qt + 1;
        for (int kvt = 0; kvt < nkv; kvt++) {
            int kv0 = kvt * 64;
            // ---- stage K tile [64][128] (4 x global_load_lds, inverse-swizzled src)
            const unsigned short* ksrc = Kb + (tok0 + kv0 + krow_l) * 256 + g * 128 + kc16 * 8;
#pragma unroll
            for (int i = 0; i < 4; i++)
                load_lds16(ksrc + (size_t)i * 16 * 256, Kl + i * 2048 + w * 512);
            // ---- stage V tile [128][64]
            const unsigned short* vsrc = Vt + (size_t)(g * 128 + vrow_l) * 4096 + b * S + kv0 + vc16 * 8;
#pragma unroll
            for (int i = 0; i < 4; i++)
                load_lds16(vsrc + (size_t)i * 32 * 4096, Vl + i * 2048 + w * 512);
            __syncthreads();

            // ---- S = Q K^T
            f32x4 sacc[4];
#pragma unroll
            for (int c = 0; c < 4; c++) sacc[c] = f32x4{0.f, 0.f, 0.f, 0.f};
            int kswz = (lr & 7) << 3;
#pragma unroll
            for (int c = 0; c < 4; c++) {
                int krow = c * 16 + lr;
#pragma unroll
                for (int ks = 0; ks < 4; ks++) {
                    bf16x8 kfr = *(const bf16x8*)&Kl[krow * 128 + ((ks * 32 + 8 * lg) ^ kswz)];
                    sacc[c] = __builtin_amdgcn_mfma_f32_16x16x32_bf16(qf[ks], kfr, sacc[c], 0, 0, 0);
                }
            }

            // ---- online softmax (rows = 4*lg + r, reduce over lr)
            bool diag = (kvt == qt);
            float p[4][4], tmax[4];
#pragma unroll
            for (int r = 0; r < 4; r++) tmax[r] = -1e30f;
#pragma unroll
            for (int c = 0; c < 4; c++)
#pragma unroll
                for (int r = 0; r < 4; r++) {
                    float s = sacc[c][r] * cexp;
                    if (diag) {
                        int qi = qrow0 + 4 * lg + r;
                        int ki = kv0 + c * 16 + lr;
                        if (ki > qi) s = -1e30f;
                    }
                    p[c][r] = s;
                    tmax[r] = fmaxf(tmax[r], s);
                }
#pragma unroll
            for (int m = 1; m < 16; m <<= 1)
#pragma unroll
                for (int r = 0; r < 4; r++)
                    tmax[r] = fmaxf(tmax[r], __shfl_xor(tmax[r], m));

            float alpha[4], tsum[4];
#pragma unroll
            for (int r = 0; r < 4; r++) {
                float mn = fmaxf(mrow[r], tmax[r]);
                alpha[r] = __builtin_exp2f(mrow[r] - mn);
                mrow[r] = mn;
                tsum[r] = 0.f;
            }
#pragma unroll
            for (int c = 0; c < 4; c++)
#pragma unroll
                for (int r = 0; r < 4; r++) {
                    float e = __builtin_exp2f(p[c][r] - mrow[r]);
                    p[c][r] = e;
                    tsum[r] += e;
                }
#pragma unroll
            for (int m = 1; m < 16; m <<= 1)
#pragma unroll
                for (int r = 0; r < 4; r++)
                    tsum[r] += __shfl_xor(tsum[r], m);
#pragma unroll
            for (int r = 0; r < 4; r++)
                lrow[r] = lrow[r] * alpha[r] + tsum[r];
#pragma unroll
            for (int t = 0; t < 8; t++)
#pragma unroll
                for (int r = 0; r < 4; r++) o[t][r] *= alpha[r];

            // ---- P -> per-wave LDS (layout change D->A frag)
#pragma unroll
            for (int c = 0; c < 4; c++)
#pragma unroll
                for (int r = 0; r < 4; r++)
                    Pl[w][4 * lg + r][c * 16 + lr] = f2bf(p[c][r]);

            // ---- O += P V
#pragma unroll
            for (int ks = 0; ks < 2; ks++) {
                bf16x8 pf = *(const bf16x8*)&Pl[w][lr][ks * 32 + 8 * lg];
#pragma unroll
                for (int t = 0; t < 8; t++) {
                    int vrow = t * 16 + lr;
                    bf16x8 vf = *(const bf16x8*)&Vl[vrow * 64 + ((ks * 32 + 8 * lg) ^ kswz)];
                    o[t] = __builtin_amdgcn_mfma_f32_16x16x32_bf16(pf, vf, o[t], 0, 0, 0);
                }
            }
            __syncthreads();   // protect Kl/Vl before next stage
        }

        // ---- epilogue
#pragma unroll
        for (int r = 0; r < 4; r++) {
            float inv = 1.0f / lrow[r];
            unsigned short* crow = Ctx + (tok0 + qrow0 + 4 * lg + r) * 2048 + h * 128;
#pragma unroll
            for (int t = 0; t < 8; t++)
                crow[t * 16 + lr] = f2bf(o[t][r] * inv);
        }
    }
}

// ---------------- launch --------------------------------------------------------------
extern "C" void kernel_launch(void* const* d_in, const int* in_sizes, int n_in,
                              void* d_out, int out_size, void* d_ws, size_t ws_size,
                              hipStream_t stream) {
    const float* x  = (const float*)d_in[0];
    const float* Wq = (const float*)d_in[1];
    const float* bq = (const float*)d_in[2];
    const float* Wk = (const float*)d_in[3];
    const float* bk = (const float*)d_in[4];
    const float* Wv = (const float*)d_in[5];
    const float* bv = (const float*)d_in[6];
    const float* gq = (const float*)d_in[7];
    const float* gk = (const float*)d_in[8];
    const float* Wo = (const float*)d_in[9];
    const float* bo = (const float*)d_in[10];
    float* out = (float*)d_out;

    char* ws = (char*)d_ws;
    size_t off = 0;
    auto alloc = [&](size_t bytes) {
        void* p = ws + off;
        off += (bytes + 255) & ~(size_t)255;
        return p;
    };
    unsigned short* wqkvt = (unsigned short*)alloc((size_t)2560 * 2048 * 2);
    unsigned short* wot   = (unsigned short*)alloc((size_t)2048 * 2048 * 2);
    unsigned short* xb    = (unsigned short*)alloc((size_t)4096 * 2048 * 2);  // reused as ctx
    float*          C     = (float*)alloc((size_t)4096 * 2560 * 4);
    unsigned short* qb_   = (unsigned short*)alloc((size_t)4096 * 2048 * 2);
    unsigned short* kb_   = (unsigned short*)alloc((size_t)4096 * 256 * 2);
    unsigned short* vt    = (unsigned short*)alloc((size_t)512 * 4096 * 2);
    float*          biascat = (float*)alloc((size_t)2560 * 4);
    unsigned short* ctx = xb;   // xb dead after proj GEMM

    // x -> bf16
    cvt_bf16_k<<<4096, 256, 0, stream>>>(x, xb, 1048576);
    // weights -> K-major bf16 (QKV fused)
    transpose_cvt2<<<dim3(64, 64), 256, 0, stream>>>(Wq, wqkvt, 2048, 2048);
    transpose_cvt2<<<dim3(8, 64),  256, 0, stream>>>(Wk, wqkvt + (size_t)2048 * 2048, 256, 2048);
    transpose_cvt2<<<dim3(8, 64),  256, 0, stream>>>(Wv, wqkvt + (size_t)2304 * 2048, 256, 2048);
    transpose_cvt2<<<dim3(64, 64), 256, 0, stream>>>(Wo, wot, 2048, 2048);
    // bias concat
    hipMemcpyAsync(biascat,        bq, 2048 * 4, hipMemcpyDeviceToDevice, stream);
    hipMemcpyAsync(biascat + 2048, bk,  256 * 4, hipMemcpyDeviceToDevice, stream);
    hipMemcpyAsync(biascat + 2304, bv,  256 * 4, hipMemcpyDeviceToDevice, stream);

    // fused QKV projection -> C f32 [4096][2560]
    gemm_lds<<<dim3(20, 32), 256, 0, stream>>>(xb, wqkvt, biascat, C, 4096, 2560, 2048);

    // per-head RMSNorm + cvt
    rmsnorm_cvt2<<<16384, 256, 0, stream>>>(C, gq, qb_, 2560, 0,    4, 65536);
    rmsnorm_cvt2<<<2048,  256, 0, stream>>>(C, gk, kb_, 2560, 2048, 1, 8192);
    // V block -> V^T bf16 [512][4096]
    transpose_cvt2<<<dim3(16, 128), 256, 0, stream>>>(C + 2304, vt, 2560, 4096);

    // attention
    attn_kernel<<<dim3(16, 16, 2), 256, 0, stream>>>(qb_, kb_, vt, ctx);

    // output projection -> f32 out
    gemm_lds<<<dim3(16, 32), 256, 0, stream>>>(ctx, wot, bo, out, 4096, 2048, 2048);
}